// Round 6
// baseline (287.699 us; speedup 1.0000x reference)
//
#include <hip/hip_runtime.h>
#include <hip/hip_bf16.h>
#include <math.h>

#define Bsz  8
#define Nseq 1024
#define Cdim 1024
#define Hh   16
#define Dd   64

typedef short short8 __attribute__((ext_vector_type(8)));
typedef float floatx4 __attribute__((ext_vector_type(4)));

__device__ __forceinline__ unsigned short f2bf(float f) {
    __hip_bfloat16 h = __float2bfloat16(f);
    return __builtin_bit_cast(unsigned short, h);
}

// async 16B global -> LDS. LDS dest is wave-uniform base + lane*16 (HW rule).
__device__ __forceinline__ void async16(const void* g, void* l) {
    __builtin_amdgcn_global_load_lds(
        (const __attribute__((address_space(1))) unsigned int*)g,
        (__attribute__((address_space(3))) unsigned int*)l, 16, 0, 0);
}

// pack two fp32 -> two bf16 (round-half-up) in one dword
__device__ __forceinline__ unsigned pack_bf16(float lo, float hi) {
    unsigned ulo = __float_as_uint(lo) + 0x8000u;
    unsigned uhi = __float_as_uint(hi) + 0x8000u;
    return __builtin_amdgcn_perm(uhi, ulo, 0x07060302);  // [ulo>>16, uhi>>16]
}

// one-instruction 2^x (we pre-fold log2(e) into the Q scale)
__device__ __forceinline__ float exp2_raw(float x) {
    float r;
    asm("v_exp_f32 %0, %1" : "=v"(r) : "v"(x));
    return r;
}

// ---------------------------------------------------------------------------
// PREP (fused): [0,8192) convert X fp32->bf16; [8192,8960) transpose w_qkv;
// [8960,9216) transpose w_proj; [9216,9344) RoPE table.
// ---------------------------------------------------------------------------
__global__ __launch_bounds__(256) void prep(
    const float* __restrict__ x, const float* __restrict__ w_qkv,
    const float* __restrict__ w_proj,
    unsigned short* __restrict__ xb, unsigned short* __restrict__ wqkvt,
    unsigned short* __restrict__ wprojt, float2* __restrict__ rope)
{
    __shared__ float T[64][65];
    const int blk = blockIdx.x;
    const int tid = threadIdx.x;

    if (blk < 8192) {
        int i = blk * 256 + tid;
        float4 v = ((const float4*)x)[i];
        ushort4 u;
        u.x = f2bf(v.x); u.y = f2bf(v.y); u.z = f2bf(v.z); u.w = f2bf(v.w);
        ((ushort4*)xb)[i] = u;
        return;
    }
    if (blk < 9216) {
        const float* in;
        unsigned short* out;
        int R = 1024, Ccols, c0, r0;
        if (blk < 8960) {
            int b2 = blk - 8192;
            in = w_qkv; out = wqkvt; Ccols = 3072;
            c0 = (b2 % 48) * 64; r0 = (b2 / 48) * 64;
        } else {
            int b2 = blk - 8960;
            in = w_proj; out = wprojt; Ccols = 1024;
            c0 = (b2 % 16) * 64; r0 = (b2 / 16) * 64;
        }
        for (int i = tid; i < 4096; i += 256) {
            int r = i >> 6, c = i & 63;
            T[r][c] = in[(size_t)(r0 + r) * Ccols + c0 + c];
        }
        __syncthreads();
        for (int i = tid; i < 4096; i += 256) {
            int rr = i >> 6, cc = i & 63;
            out[(size_t)(c0 + rr) * R + r0 + cc] = f2bf(T[cc][rr]);
        }
        return;
    }
    {
        int i = (blk - 9216) * 256 + tid;     // 0..32767
        int n = i >> 5, p = i & 31;
        float omega = __expf(-(float)p * 0.2878231366242557f);
        float sv, cv;
        sincosf((float)n * omega, &sv, &cv);
        rope[i] = make_float2(cv, sv);
    }
}

// ---------------------------------------------------------------------------
// QKV GEMM with A-reuse, spill-proof geometry: 512 threads / 8 waves,
// wave-tile 64x32 per region, acc[3][4][2] = 96 VGPR (fits < 128 ceiling ->
// 16 waves/CU, 2 blocks/CU, LDS-bound). Each block: one 128-row A-tile x
// three 128-col B-tiles (q,k,v) in one K-loop -> 48 MFMA per wave per
// barrier-pair (1.5x round-2) at the same 8 staging insts/wave.
// Grid 512 blocks = exactly 2/CU x 256 CU = one residency round.
// LDS 64 KB: As[128][64] @0, Bs[rg][128][64] @8192+rg*8192 (shorts).
// XOR swizzle (slot c of row r at c^(r&7), via pre-swizzled source).
// Epilogue: RoPE-scatter q,k (shared Rs slice); LDS-transpose v -> vt.
// Q pre-scale = 0.125*log2(e) so attention uses raw v_exp_f32.
// ---------------------------------------------------------------------------
__global__ __launch_bounds__(512, 4) void gemm_qkv(
    const unsigned short* __restrict__ A, const unsigned short* __restrict__ Bt,
    const float2* __restrict__ rope,
    unsigned short* __restrict__ qb, unsigned short* __restrict__ kb,
    unsigned short* __restrict__ vtb)
{
    __shared__ __attribute__((aligned(16))) short SM[32768];   // 64 KB
    const int tid  = threadIdx.x;
    const int wave = tid >> 6, lane = tid & 63;
    const int ml = lane & 15, quad = lane >> 4;
    const int wm = wave >> 2, wn = wave & 3;      // 2 x 4 wave grid

    // XCD-aware bijective remap (512 blocks, %8==0)
    int lin = blockIdx.y * 8 + blockIdx.x;
    lin = (lin & 7) * 64 + (lin >> 3);
    const int bm = (lin >> 3) * 128;          // 0..8063
    const int bn = (lin & 7) * 128;           // 0..895

    const int lr     = lane >> 3;                 // row within 8-row group
    const int lchunk = ((lane & 7) ^ lr) * 8;     // swizzled source chunk (shorts)

    floatx4 acc[3][4][2] = {};

    for (int k0 = 0; k0 < 1024; k0 += 64) {
        // stage A (128 rows) + B0,B1,B2 (128 rows each): 2 insts per array/wave
        #pragma unroll
        for (int t = 0; t < 2; ++t) {
            int r8 = (wave * 2 + t) * 8;          // 0..120
            async16(A + (size_t)(bm + r8 + lr) * 1024 + k0 + lchunk, &SM[r8 * 64]);
            #pragma unroll
            for (int rg = 0; rg < 3; ++rg)
                async16(Bt + (size_t)(rg * 1024 + bn + r8 + lr) * 1024 + k0 + lchunk,
                        &SM[8192 + rg * 8192 + r8 * 64]);
        }
        __syncthreads();

        #pragma unroll
        for (int ks = 0; ks < 2; ++ks) {
            const int sl = ((ks * 4 + quad) ^ (ml & 7)) * 8;
            short8 araw[4];
            #pragma unroll
            for (int mi = 0; mi < 4; ++mi)
                araw[mi] = *(const short8*)&SM[(wm * 64 + mi * 16 + ml) * 64 + sl];
            #pragma unroll
            for (int rg = 0; rg < 3; ++rg) {
                short8 braw[2];
                #pragma unroll
                for (int ni = 0; ni < 2; ++ni)
                    braw[ni] = *(const short8*)&SM[8192 + rg * 8192 +
                                                   (wn * 32 + ni * 16 + ml) * 64 + sl];
                #pragma unroll
                for (int mi = 0; mi < 4; ++mi)
                    #pragma unroll
                    for (int ni = 0; ni < 2; ++ni)
                        acc[rg][mi][ni] = __builtin_amdgcn_mfma_f32_16x16x32_bf16(
                            araw[mi], braw[ni], acc[rg][mi][ni], 0, 0, 0);
            }
        }
        __syncthreads();   // frag reads done before next stage / epilogue reuse
    }

    // ---- epilogue: q-scatter, k-scatter (shared Rs), v-transpose ----
    const int b  = bm >> 10;
    const int n0 = bm & 1023;

    float2* Rs = (float2*)SM;                 // 4096 float2 = 32 KB (shorts [0,16384))
    #pragma unroll
    for (int t = 0; t < 8; ++t) {
        int idx = t * 512 + tid;
        Rs[idx] = rope[(size_t)(n0 + (idx >> 5)) * 32 + (idx & 31)];
    }
    __syncthreads();

    #pragma unroll
    for (int rg = 0; rg < 2; ++rg) {
        unsigned short* dst = (rg == 0) ? qb : kb;
        // q: 0.125 * log2(e) so attn uses raw v_exp_f32 (2^x)
        const float scale = (rg == 0) ? 0.1803368801111602f : 1.f;
        const float sgn = (ml & 1) ? 1.f : -1.f;
        #pragma unroll
        for (int ni = 0; ni < 2; ++ni) {
            int jj = bn + wn * 32 + ni * 16 + ml;
            int h = jj >> 6, d = jj & 63, p = d >> 1;
            #pragma unroll
            for (int mi = 0; mi < 4; ++mi)
                #pragma unroll
                for (int r = 0; r < 4; ++r) {
                    int rl = wm * 64 + mi * 16 + quad * 4 + r;
                    float val = acc[rg][mi][ni][r];
                    float partner = __shfl_xor(val, 1);
                    float2 cs = Rs[rl * 32 + p];
                    dst[(((size_t)(b * Hh + h)) * Nseq + n0 + rl) * Dd + d] =
                        f2bf((val * cs.x + sgn * partner * cs.y) * scale);
                }
        }
    }

    // V: transpose via LDS T[64][132] (shorts @16384, disjoint from Rs)
    {
        short* T = SM + 16384;
        #pragma unroll
        for (int hw = 0; hw < 2; ++hw) {
            if (hw) __syncthreads();          // prior half's copies done
            if ((wn >> 1) == hw) {            // 4 waves own this 64-col half
                #pragma unroll
                for (int ni = 0; ni < 2; ++ni) {
                    int dcol = (wn & 1) * 32 + ni * 16 + ml;
                    #pragma unroll
                    for (int mi = 0; mi < 4; ++mi) {
                        uint2 pk;
                        pk.x = pack_bf16(acc[2][mi][ni][0], acc[2][mi][ni][1]);
                        pk.y = pack_bf16(acc[2][mi][ni][2], acc[2][mi][ni][3]);
                        *(uint2*)&T[dcol * 132 + wm * 64 + mi * 16 + quad * 4] = pk;
                    }
                }
            }
            __syncthreads();
            int h = (bn >> 6) + hw;
            #pragma unroll
            for (int t = 0; t < 4; ++t) {
                int idx4 = t * 512 + tid;     // 0..2047 ushort4 units
                int d = idx4 >> 5, seg = idx4 & 31;
                ushort4 v4 = *(const ushort4*)&T[d * 132 + seg * 4];
                *(ushort4*)(vtb + (((size_t)(b * Hh + h)) * Dd + d) * Nseq
                            + n0 + seg * 4) = v4;
            }
        }
    }
}

// ---------------------------------------------------------------------------
// Output-projection GEMM (proven m97-style 128x128, BK=64, 4 waves): +bias,
// fp32 out. XCD-aware block swizzle (512 blocks % 8 == 0).
// ---------------------------------------------------------------------------
__global__ __launch_bounds__(256) void gemm_proj(
    const unsigned short* __restrict__ A, const unsigned short* __restrict__ Bt,
    const float* __restrict__ bias, float* __restrict__ out)
{
    const int K = 1024;
    __shared__ short SM[2][128][64];
    const int tid  = threadIdx.x;
    const int wave = tid >> 6, lane = tid & 63;
    const int ml = lane & 15, quad = lane >> 4;
    const int wm = wave >> 1, wn = wave & 1;

    int lin = blockIdx.y * gridDim.x + blockIdx.x;
    const int nwg = gridDim.x * gridDim.y;
    lin = (lin & 7) * (nwg >> 3) + (lin >> 3);
    const int bx = lin % gridDim.x, by = lin / gridDim.x;
    const int bm = by * 128, bn = bx * 128;

    const int lr     = lane >> 3;
    const int lchunk = ((lane & 7) ^ lr) * 8;

    floatx4 acc[4][4] = {};

    for (int k0 = 0; k0 < K; k0 += 64) {
        #pragma unroll
        for (int t = 0; t < 4; ++t) {
            int r8  = (wave * 4 + t) * 8;
            int row = r8 + lr;
            async16(A  + (size_t)(bm + row) * K + k0 + lchunk, &SM[0][r8][0]);
            async16(Bt + (size_t)(bn + row) * K + k0 + lchunk, &SM[1][r8][0]);
        }
        __syncthreads();

        #pragma unroll
        for (int ks = 0; ks < 2; ++ks) {
            const int sl = ((ks * 4 + quad) ^ (ml & 7)) * 8;
            short8 araw[4], braw[4];
            #pragma unroll
            for (int mi = 0; mi < 4; ++mi)
                araw[mi] = *(const short8*)&SM[0][wm * 64 + mi * 16 + ml][sl];
            #pragma unroll
            for (int ni = 0; ni < 4; ++ni)
                braw[ni] = *(const short8*)&SM[1][wn * 64 + ni * 16 + ml][sl];
            #pragma unroll
            for (int mi = 0; mi < 4; ++mi)
                #pragma unroll
                for (int ni = 0; ni < 4; ++ni)
                    acc[mi][ni] = __builtin_amdgcn_mfma_f32_16x16x32_bf16(
                        araw[mi], braw[ni], acc[mi][ni], 0, 0, 0);
        }
        __syncthreads();
    }

    #pragma unroll
    for (int ni = 0; ni < 4; ++ni) {
        int col = bn + wn * 64 + ni * 16 + ml;
        float bv = bias[col];
        #pragma unroll
        for (int mi = 0; mi < 4; ++mi)
            #pragma unroll
            for (int r = 0; r < 4; ++r) {
                int row = bm + wm * 64 + mi * 16 + quad * 4 + r;
                out[(size_t)row * 1024 + col] = acc[mi][ni][r] + bv;
            }
    }
}

// ---------------------------------------------------------------------------
// MFMA flash attention (round-2 proven version): no-max softmax, 128 q-rows
// per block, software-pipelined V(kt)/K(kt+1) staging, Q fragments hoisted,
// LDS union (34 KB -> 4 blocks/CU), setprio around MFMA clusters.
// exp path: Q pre-scaled by 0.125*log2(e) upstream -> bare v_exp_f32 here.
// ---------------------------------------------------------------------------
__global__ __launch_bounds__(256, 4) void attn_flash_mfma(
    const unsigned short* __restrict__ qb, const unsigned short* __restrict__ kb,
    const unsigned short* __restrict__ vt, unsigned short* __restrict__ ao)
{
    const int bh  = blockIdx.x;   // 0..127
    const int qt  = blockIdx.y;   // 0..7
    const int tid = threadIdx.x;
    const int wave = tid >> 6, lane = tid & 63;
    const int ml = lane & 15, quad = lane >> 4;
    const int lr = lane >> 3;
    const int lc = ((lane & 7) ^ lr) * 8;

    // 34 KB total: Ks[64][64] | U = union{ Qs[128][64] (prologue only),
    //                                      Vs[64][64] + Ps[4][32][72] }
    __shared__ __attribute__((aligned(16))) short SMEM[17408];
    short (*Ks)[64] = (short(*)[64])SMEM;                 // 4096 shorts
    short* U = SMEM + 4096;
    short (*Qs)[64] = (short(*)[64])U;                    // prologue only
    short (*Vs)[64] = (short(*)[64])U;                    // 4096 shorts
    short (*Ps)[32][72] = (short(*)[32][72])(U + 4096);   // 9216 shorts

    const size_t hbase = (size_t)bh * (Nseq * Dd);
    const size_t vbase = (size_t)bh * 64;
    const int q0 = qt * 128;
    const int wq = wave * 32;
    const int wk = wave * 16;

    #pragma unroll
    for (int t = 0; t < 4; ++t)
        async16(qb + hbase + (size_t)(q0 + wq + t * 8 + lr) * 64 + lc, &Qs[wq + t * 8][0]);
    async16(kb + hbase + (size_t)(wk + lr) * 64 + lc,     &Ks[wk][0]);
    async16(kb + hbase + (size_t)(wk + 8 + lr) * 64 + lc, &Ks[wk + 8][0]);
    __syncthreads();

    short8 qfr[2][2];
    #pragma unroll
    for (int ks = 0; ks < 2; ++ks) {
        const int sl = ((ks * 4 + quad) ^ (ml & 7)) * 8;
        qfr[ks][0] = *(const short8*)&Qs[wq + ml][sl];
        qfr[ks][1] = *(const short8*)&Qs[wq + 16 + ml][sl];
    }
    __syncthreads();   // qfr reads complete in all waves: U reusable (Vs/Ps)

    float l0 = 0.f, l1 = 0.f;
    floatx4 o[2][4] = {};

    for (int kt = 0; kt < 16; ++kt) {
        const int k0r = kt * 64;
        async16(vt + (vbase + wk + lr) * Nseq + k0r + lc,     &Vs[wk][0]);
        async16(vt + (vbase + wk + 8 + lr) * Nseq + k0r + lc, &Vs[wk + 8][0]);

        floatx4 st[2][4] = {};
        __builtin_amdgcn_s_setprio(1);
        #pragma unroll
        for (int ks = 0; ks < 2; ++ks) {
            const int sl = ((ks * 4 + quad) ^ (ml & 7)) * 8;
            #pragma unroll
            for (int kbk = 0; kbk < 4; ++kbk) {
                short8 kf = *(const short8*)&Ks[kbk * 16 + ml][sl];
                st[0][kbk] = __builtin_amdgcn_mfma_f32_16x16x32_bf16(kf, qfr[ks][0], st[0][kbk], 0, 0, 0);
                st[1][kbk] = __builtin_amdgcn_mfma_f32_16x16x32_bf16(kf, qfr[ks][1], st[1][kbk], 0, 0, 0);
            }
        }
        __builtin_amdgcn_s_setprio(0);

        #pragma unroll
        for (int qg = 0; qg < 2; ++qg) {
            float lacc = 0.f;
            #pragma unroll
            for (int kbk = 0; kbk < 4; ++kbk) {
                float e0 = exp2_raw(st[qg][kbk][0]);
                float e1 = exp2_raw(st[qg][kbk][1]);
                float e2 = exp2_raw(st[qg][kbk][2]);
                float e3 = exp2_raw(st[qg][kbk][3]);
                lacc += (e0 + e1) + (e2 + e3);
                uint2 pk;
                pk.x = pack_bf16(e0, e1);
                pk.y = pack_bf16(e2, e3);
                *(uint2*)&Ps[wave][qg * 16 + ml][kbk * 16 + quad * 4] = pk;
            }
            if (qg == 0) l0 += lacc; else l1 += lacc;
        }
        __syncthreads();   // V(kt) visible; all waves done with Ks(kt)

        if (kt < 15) {
            const int k1r = k0r + 64;
            async16(kb + hbase + (size_t)(k1r + wk + lr) * 64 + lc,     &Ks[wk][0]);
            async16(kb + hbase + (size_t)(k1r + wk + 8 + lr) * 64 + lc, &Ks[wk + 8][0]);
        }

        __builtin_amdgcn_s_setprio(1);
        #pragma unroll
        for (int ks = 0; ks < 2; ++ks) {
            const int sl = ((ks * 4 + quad) ^ (ml & 7)) * 8;
            short8 pf0 = *(const short8*)&Ps[wave][ml][ks * 32 + quad * 8];
            short8 pf1 = *(const short8*)&Ps[wave][16 + ml][ks * 32 + quad * 8];
            #pragma unroll
            for (int nt = 0; nt < 4; ++nt) {
                short8 vf = *(const short8*)&Vs[nt * 16 + ml][sl];
                o[0][nt] = __builtin_amdgcn_mfma_f32_16x16x32_bf16(pf0, vf, o[0][nt], 0, 0, 0);
                o[1][nt] = __builtin_amdgcn_mfma_f32_16x16x32_bf16(pf1, vf, o[1][nt], 0, 0, 0);
            }
        }
        __builtin_amdgcn_s_setprio(0);
        if (kt < 15)
            __syncthreads();
    }

    l0 += __shfl_xor(l0, 16);
    l0 += __shfl_xor(l0, 32);
    l1 += __shfl_xor(l1, 16);
    l1 += __shfl_xor(l1, 32);

    const int b = bh >> 4, h = bh & 15;
    #pragma unroll
    for (int qg = 0; qg < 2; ++qg) {
        float lsrc = (qg == 0) ? l0 : l1;
        #pragma unroll
        for (int r = 0; r < 4; ++r) {
            float lq = __shfl(lsrc, quad * 4 + r);
            float inv = 1.f / lq;
            int q = q0 + wq + qg * 16 + quad * 4 + r;
            size_t rowbase = ((size_t)(b * Nseq + q)) * Cdim + h * Dd;
            #pragma unroll
            for (int nt = 0; nt < 4; ++nt)
                ao[rowbase + nt * 16 + ml] = f2bf(o[qg][nt][r] * inv);
        }
    }
}

extern "C" void kernel_launch(void* const* d_in, const int* in_sizes, int n_in,
                              void* d_out, int out_size, void* d_ws, size_t ws_size,
                              hipStream_t stream) {
    const float* x      = (const float*)d_in[0];
    const float* w_qkv  = (const float*)d_in[1];
    const float* w_proj = (const float*)d_in[2];
    const float* b_proj = (const float*)d_in[3];
    float* out = (float*)d_out;

    const size_t M8 = (size_t)8 * 1024 * 1024;
    unsigned short* qb     = (unsigned short*)d_ws;
    unsigned short* kb     = qb + M8;
    unsigned short* vt     = kb + M8;                  // (B,H,D,N)
    unsigned short* xb     = vt + M8;                  // reused as aob
    unsigned short* wqkvt  = xb + M8;                  // 3072 x 1024
    unsigned short* wprojt = wqkvt + 3 * 1024 * 1024;  // 1024 x 1024
    float2*         rope   = (float2*)(wprojt + 1024 * 1024);  // 1024 x 32
    unsigned short* aob    = xb;   // alias: xb dead after gemm_qkv

    prep<<<9344, 256, 0, stream>>>(x, w_qkv, w_proj, xb, wqkvt, wprojt, rope);

    gemm_qkv<<<dim3(8, 64), 512, 0, stream>>>(xb, wqkvt, rope, qb, kb, vt);

    attn_flash_mfma<<<dim3(128, 8), 256, 0, stream>>>(qb, kb, vt, aob);

    gemm_proj<<<dim3(8, 64), 256, 0, stream>>>(aob, wprojt, b_proj, out);
}

// Round 7
// 243.301 us; speedup vs baseline: 1.1825x; 1.1825x over previous
//
#include <hip/hip_runtime.h>
#include <hip/hip_bf16.h>
#include <math.h>

#define Bsz  8
#define Nseq 1024
#define Cdim 1024
#define Hh   16
#define Dd   64

typedef short short8 __attribute__((ext_vector_type(8)));
typedef float floatx4 __attribute__((ext_vector_type(4)));

__device__ __forceinline__ unsigned short f2bf(float f) {
    __hip_bfloat16 h = __float2bfloat16(f);
    return __builtin_bit_cast(unsigned short, h);
}

// async 16B global -> LDS. LDS dest is wave-uniform base + lane*16 (HW rule).
__device__ __forceinline__ void async16(const void* g, void* l) {
    __builtin_amdgcn_global_load_lds(
        (const __attribute__((address_space(1))) unsigned int*)g,
        (__attribute__((address_space(3))) unsigned int*)l, 16, 0, 0);
}

// pack two fp32 -> two bf16 (round-half-up) in one dword
__device__ __forceinline__ unsigned pack_bf16(float lo, float hi) {
    unsigned ulo = __float_as_uint(lo) + 0x8000u;
    unsigned uhi = __float_as_uint(hi) + 0x8000u;
    return __builtin_amdgcn_perm(uhi, ulo, 0x07060302);  // [ulo>>16, uhi>>16]
}

// one-instruction 2^x (log2(e) is pre-folded into the Q scale)
__device__ __forceinline__ float exp2_raw(float x) {
    float r;
    asm("v_exp_f32 %0, %1" : "=v"(r) : "v"(x));
    return r;
}

// ---------------------------------------------------------------------------
// PREP (fused): [0,8192) convert X fp32->bf16; [8192,8960) transpose w_qkv;
// [8960,9216) transpose w_proj; [9216,9344) RoPE table.
// ---------------------------------------------------------------------------
__global__ __launch_bounds__(256) void prep(
    const float* __restrict__ x, const float* __restrict__ w_qkv,
    const float* __restrict__ w_proj,
    unsigned short* __restrict__ xb, unsigned short* __restrict__ wqkvt,
    unsigned short* __restrict__ wprojt, float2* __restrict__ rope)
{
    __shared__ float T[64][65];
    const int blk = blockIdx.x;
    const int tid = threadIdx.x;

    if (blk < 8192) {
        int i = blk * 256 + tid;
        float4 v = ((const float4*)x)[i];
        ushort4 u;
        u.x = f2bf(v.x); u.y = f2bf(v.y); u.z = f2bf(v.z); u.w = f2bf(v.w);
        ((ushort4*)xb)[i] = u;
        return;
    }
    if (blk < 9216) {
        const float* in;
        unsigned short* out;
        int R = 1024, Ccols, c0, r0;
        if (blk < 8960) {
            int b2 = blk - 8192;
            in = w_qkv; out = wqkvt; Ccols = 3072;
            c0 = (b2 % 48) * 64; r0 = (b2 / 48) * 64;
        } else {
            int b2 = blk - 8960;
            in = w_proj; out = wprojt; Ccols = 1024;
            c0 = (b2 % 16) * 64; r0 = (b2 / 16) * 64;
        }
        for (int i = tid; i < 4096; i += 256) {
            int r = i >> 6, c = i & 63;
            T[r][c] = in[(size_t)(r0 + r) * Ccols + c0 + c];
        }
        __syncthreads();
        for (int i = tid; i < 4096; i += 256) {
            int rr = i >> 6, cc = i & 63;
            out[(size_t)(c0 + rr) * R + r0 + cc] = f2bf(T[cc][rr]);
        }
        return;
    }
    {
        int i = (blk - 9216) * 256 + tid;     // 0..32767
        int n = i >> 5, p = i & 31;
        float omega = __expf(-(float)p * 0.2878231366242557f);
        float sv, cv;
        sincosf((float)n * omega, &sv, &cv);
        rope[i] = make_float2(cv, sv);
    }
}

// ---------------------------------------------------------------------------
// bf16 MFMA GEMM, BK=64 (16 K-iters, 32 KB LDS, XOR swizzle, XCD-aware
// block remap). Proven round-2 version (~80 us for MODE 0).
// MODE 0: N=3072; epilogue RoPE-scatters q,k -> (B,H,N,D); v -> vt (B,H,D,N).
//         q is pre-scaled by 0.125*log2(e) so attention uses raw v_exp_f32.
// MODE 1: N=1024, +bias -> fp32 out.
// ---------------------------------------------------------------------------
template <int MODE>
__global__ __launch_bounds__(256) void gemm_bf16(
    const unsigned short* __restrict__ A, const unsigned short* __restrict__ Bt,
    const float* __restrict__ bias, const float2* __restrict__ rope,
    unsigned short* __restrict__ qb, unsigned short* __restrict__ kb,
    unsigned short* __restrict__ vtb, float* __restrict__ out)
{
    const int K = 1024;
    __shared__ short SM[2][128][64];   // [0]=As, [1]=Bs; reused by epilogue
    const int tid  = threadIdx.x;
    const int wave = tid >> 6, lane = tid & 63;
    const int ml = lane & 15, quad = lane >> 4;
    const int wm = wave >> 1, wn = wave & 1;

    // XCD-aware bijective remap (nwg % 8 == 0 for both modes)
    int lin = blockIdx.y * gridDim.x + blockIdx.x;
    const int nwg = gridDim.x * gridDim.y;
    lin = (lin & 7) * (nwg >> 3) + (lin >> 3);
    const int bx = lin % gridDim.x, by = lin / gridDim.x;
    const int bm = by * 128, bn = bx * 128;

    const int lr     = lane >> 3;                 // row within 8-row group
    const int lchunk = ((lane & 7) ^ lr) * 8;     // swizzled source chunk (shorts)

    floatx4 acc[4][4] = {};

    for (int k0 = 0; k0 < K; k0 += 64) {
        #pragma unroll
        for (int t = 0; t < 4; ++t) {
            int r8  = (wave * 4 + t) * 8;
            int row = r8 + lr;
            async16(A  + (size_t)(bm + row) * K + k0 + lchunk, &SM[0][r8][0]);
            async16(Bt + (size_t)(bn + row) * K + k0 + lchunk, &SM[1][r8][0]);
        }
        __syncthreads();

        #pragma unroll
        for (int ks = 0; ks < 2; ++ks) {
            const int sl = ((ks * 4 + quad) ^ (ml & 7)) * 8;
            short8 araw[4], braw[4];
            #pragma unroll
            for (int mi = 0; mi < 4; ++mi)
                araw[mi] = *(const short8*)&SM[0][wm * 64 + mi * 16 + ml][sl];
            #pragma unroll
            for (int ni = 0; ni < 4; ++ni)
                braw[ni] = *(const short8*)&SM[1][wn * 64 + ni * 16 + ml][sl];
            #pragma unroll
            for (int mi = 0; mi < 4; ++mi)
                #pragma unroll
                for (int ni = 0; ni < 4; ++ni)
                    acc[mi][ni] = __builtin_amdgcn_mfma_f32_16x16x32_bf16(
                        araw[mi], braw[ni], acc[mi][ni], 0, 0, 0);
        }
        __syncthreads();   // frag reads done before next stage / epilogue reuse
    }

    if (MODE == 0) {
        const int region = bn >> 10;              // 0=q, 1=k, 2=v (block-uniform)
        const int b = bm >> 10;
        if (region < 2) {
            // stage rope slice for rows bm..bm+127: Rs[rl][p], 4096 float2 = 32 KB
            float2* Rs = (float2*)&SM[0][0][0];
            #pragma unroll
            for (int t = 0; t < 16; ++t) {
                int idx = t * 256 + tid;
                Rs[idx] = rope[(size_t)((bm + (idx >> 5)) & 1023) * 32 + (idx & 31)];
            }
            __syncthreads();
            unsigned short* dst = (region == 0) ? qb : kb;
            const float scale = (region == 0) ? 0.1803368801111602f : 1.f;
            const float sgn = (ml & 1) ? 1.f : -1.f;
            #pragma unroll
            for (int ni = 0; ni < 4; ++ni) {
                int col = bn + wn * 64 + ni * 16 + ml;
                int jj = col & 1023;
                int h = jj >> 6, d = jj & 63;
                int p = d >> 1;
                #pragma unroll
                for (int mi = 0; mi < 4; ++mi)
                    #pragma unroll
                    for (int r = 0; r < 4; ++r) {
                        int rl = wm * 64 + mi * 16 + quad * 4 + r;
                        int n  = (bm + rl) & 1023;
                        float val = acc[mi][ni][r];
                        float partner = __shfl_xor(val, 1);
                        float2 cs = Rs[rl * 32 + p];
                        dst[(((size_t)(b * Hh + h)) * Nseq + n) * Dd + d] =
                            f2bf((val * cs.x + sgn * partner * cs.y) * scale);
                    }
            }
        } else {
            // V: transpose via LDS (two 64-col halves), store (B,H,D,N) coalesced
            short* T = &SM[0][0][0];              // [64][132] = 16.9 KB
            const int n0 = bm & 1023;
            #pragma unroll
            for (int hw = 0; hw < 2; ++hw) {
                if (hw) __syncthreads();          // prior half's reads done
                if (wn == hw) {
                    #pragma unroll
                    for (int ni = 0; ni < 4; ++ni) {
                        int dcol = ni * 16 + ml;
                        #pragma unroll
                        for (int mi = 0; mi < 4; ++mi)
                            #pragma unroll
                            for (int r = 0; r < 4; ++r) {
                                int rl = wm * 64 + mi * 16 + quad * 4 + r;
                                T[dcol * 132 + rl] = (short)f2bf(acc[mi][ni][r]);
                            }
                    }
                }
                __syncthreads();
                int h = ((bn & 1023) >> 6) + hw;
                #pragma unroll
                for (int t = 0; t < 8; ++t) {
                    int idx4 = t * 256 + tid;     // 0..2047 ushort4 units
                    int d = idx4 >> 5, seg = idx4 & 31;
                    ushort4 v4 = *(const ushort4*)&T[d * 132 + seg * 4];
                    *(ushort4*)(vtb + (((size_t)(b * Hh + h)) * Dd + d) * Nseq
                                + n0 + seg * 4) = v4;
                }
            }
        }
    } else {
        #pragma unroll
        for (int ni = 0; ni < 4; ++ni) {
            int col = bn + wn * 64 + ni * 16 + ml;
            float bv = bias[col];
            #pragma unroll
            for (int mi = 0; mi < 4; ++mi)
                #pragma unroll
                for (int r = 0; r < 4; ++r) {
                    int row = bm + wm * 64 + mi * 16 + quad * 4 + r;
                    out[(size_t)row * 1024 + col] = acc[mi][ni][r] + bv;
                }
        }
    }
}

// ---------------------------------------------------------------------------
// MFMA flash attention, round-7: Ps LDS buffer ELIMINATED — PV A-fragments
// built in-register from the QK^T accumulators via ds_bpermute (T12-style):
// lane(ml,quad) holds P[q=ml][16*kbk+4*quad+r]; PV needs keys
// 32*ks+8*quad+{0..7} = dwords of lanes srcA=ml+32*(quad&1), srcB=srcA+16
// with kbk=2*ks+(quad>>1) (both kbk shuffled, selected locally).
// K and V double-buffered in 32 KB (Qs unioned over buffer 1) -> 4 blocks/CU
// retained AND a single vmcnt(0)+barrier per KV tile (was two full drains).
// Q pre-scaled by 0.125*log2(e) -> bare v_exp_f32 for the softmax exp.
// ---------------------------------------------------------------------------
__global__ __launch_bounds__(256, 4) void attn_flash_mfma(
    const unsigned short* __restrict__ qb, const unsigned short* __restrict__ kb,
    const unsigned short* __restrict__ vt, unsigned short* __restrict__ ao)
{
    const int bh  = blockIdx.x;   // 0..127
    const int qt  = blockIdx.y;   // 0..7
    const int tid = threadIdx.x;
    const int wave = tid >> 6, lane = tid & 63;
    const int ml = lane & 15, quad = lane >> 4;
    const int lr = lane >> 3;
    const int lc = ((lane & 7) ^ lr) * 8;

    // 32 KB: buffer b @ SMEM + b*8192 shorts = { Ks[64][64] @+0, Vs[64][64] @+4096 }
    // Qs[128][64] (prologue only) occupies the buffer-1 region.
    __shared__ __attribute__((aligned(16))) short SMEM[16384];
    short (*Qs)[64] = (short(*)[64])(SMEM + 8192);

    const size_t hbase = (size_t)bh * (Nseq * Dd);
    const size_t vbase = (size_t)bh * 64;
    const int q0 = qt * 128;
    const int wq = wave * 32;
    const int wk = wave * 16;

    // prologue: Q (4) -> buf1 region, K0/V0 (4) -> buf0
    #pragma unroll
    for (int t = 0; t < 4; ++t)
        async16(qb + hbase + (size_t)(q0 + wq + t * 8 + lr) * 64 + lc, &Qs[wq + t * 8][0]);
    async16(kb + hbase + (size_t)(wk + lr) * 64 + lc,     SMEM + (wk) * 64);
    async16(kb + hbase + (size_t)(wk + 8 + lr) * 64 + lc, SMEM + (wk + 8) * 64);
    async16(vt + (vbase + wk + lr) * Nseq + lc,           SMEM + 4096 + (wk) * 64);
    async16(vt + (vbase + wk + 8 + lr) * Nseq + lc,       SMEM + 4096 + (wk + 8) * 64);
    __syncthreads();

    short8 qfr[2][2];
    #pragma unroll
    for (int ks = 0; ks < 2; ++ks) {
        const int sl = ((ks * 4 + quad) ^ (ml & 7)) * 8;
        qfr[ks][0] = *(const short8*)&Qs[wq + ml][sl];
        qfr[ks][1] = *(const short8*)&Qs[wq + 16 + ml][sl];
    }
    __syncthreads();   // all Qs reads done in all waves: buf1 free for staging

    float l0 = 0.f, l1 = 0.f;
    floatx4 o[2][4] = {};
    const int srcA = ml + ((quad & 1) << 5);
    const int srcB = srcA + 16;

    for (int kt = 0; kt < 16; ++kt) {
        const short* Kb = SMEM + (kt & 1) * 8192;
        const short* Vb = Kb + 4096;

        if (kt < 15) {   // stage next tile into the other buffer (dead region)
            short* Nb = SMEM + ((kt & 1) ^ 1) * 8192;
            const int k1r = (kt + 1) * 64;
            async16(kb + hbase + (size_t)(k1r + wk + lr) * 64 + lc,     Nb + (wk) * 64);
            async16(kb + hbase + (size_t)(k1r + wk + 8 + lr) * 64 + lc, Nb + (wk + 8) * 64);
            async16(vt + (vbase + wk + lr) * Nseq + k1r + lc,           Nb + 4096 + (wk) * 64);
            async16(vt + (vbase + wk + 8 + lr) * Nseq + k1r + lc,       Nb + 4096 + (wk + 8) * 64);
        }

        floatx4 st[2][4] = {};
        __builtin_amdgcn_s_setprio(1);
        #pragma unroll
        for (int ks = 0; ks < 2; ++ks) {
            const int sl = ((ks * 4 + quad) ^ (ml & 7)) * 8;
            #pragma unroll
            for (int kbk = 0; kbk < 4; ++kbk) {
                short8 kf = *(const short8*)&Kb[(kbk * 16 + ml) * 64 + sl];
                st[0][kbk] = __builtin_amdgcn_mfma_f32_16x16x32_bf16(kf, qfr[ks][0], st[0][kbk], 0, 0, 0);
                st[1][kbk] = __builtin_amdgcn_mfma_f32_16x16x32_bf16(kf, qfr[ks][1], st[1][kbk], 0, 0, 0);
            }
        }
        __builtin_amdgcn_s_setprio(0);

        uint2 pk[2][4];
        #pragma unroll
        for (int qg = 0; qg < 2; ++qg) {
            float lacc = 0.f;
            #pragma unroll
            for (int kbk = 0; kbk < 4; ++kbk) {
                float e0 = exp2_raw(st[qg][kbk][0]);
                float e1 = exp2_raw(st[qg][kbk][1]);
                float e2 = exp2_raw(st[qg][kbk][2]);
                float e3 = exp2_raw(st[qg][kbk][3]);
                lacc += (e0 + e1) + (e2 + e3);
                pk[qg][kbk].x = pack_bf16(e0, e1);
                pk[qg][kbk].y = pack_bf16(e2, e3);
            }
            if (qg == 0) l0 += lacc; else l1 += lacc;
        }

        __builtin_amdgcn_s_setprio(1);
        #pragma unroll
        for (int ks = 0; ks < 2; ++ks) {
            const int sl = ((ks * 4 + quad) ^ (ml & 7)) * 8;
            short8 pf[2];
            #pragma unroll
            for (int qg = 0; qg < 2; ++qg) {
                int alx = __shfl((int)pk[qg][2 * ks].x,     srcA);
                int aly = __shfl((int)pk[qg][2 * ks].y,     srcA);
                int ahx = __shfl((int)pk[qg][2 * ks + 1].x, srcA);
                int ahy = __shfl((int)pk[qg][2 * ks + 1].y, srcA);
                int blx = __shfl((int)pk[qg][2 * ks].x,     srcB);
                int bly = __shfl((int)pk[qg][2 * ks].y,     srcB);
                int bhx = __shfl((int)pk[qg][2 * ks + 1].x, srcB);
                int bhy = __shfl((int)pk[qg][2 * ks + 1].y, srcB);
                const bool up = (quad >> 1) != 0;   // kbk = 2*ks + (quad>>1)
                int4 dv;
                dv.x = up ? ahx : alx;
                dv.y = up ? ahy : aly;
                dv.z = up ? bhx : blx;
                dv.w = up ? bhy : bly;
                pf[qg] = __builtin_bit_cast(short8, dv);
            }
            #pragma unroll
            for (int nt = 0; nt < 4; ++nt) {
                short8 vf = *(const short8*)&Vb[(nt * 16 + ml) * 64 + sl];
                o[0][nt] = __builtin_amdgcn_mfma_f32_16x16x32_bf16(pf[0], vf, o[0][nt], 0, 0, 0);
                o[1][nt] = __builtin_amdgcn_mfma_f32_16x16x32_bf16(pf[1], vf, o[1][nt], 0, 0, 0);
            }
        }
        __builtin_amdgcn_s_setprio(0);

        if (kt < 15) {
            // own staging (issued at iteration top) retired; publish block-wide
            asm volatile("s_waitcnt vmcnt(0)" ::: "memory");
            __builtin_amdgcn_s_barrier();
        }
    }

    l0 += __shfl_xor(l0, 16);
    l0 += __shfl_xor(l0, 32);
    l1 += __shfl_xor(l1, 16);
    l1 += __shfl_xor(l1, 32);

    const int b = bh >> 4, h = bh & 15;
    #pragma unroll
    for (int qg = 0; qg < 2; ++qg) {
        float lsrc = (qg == 0) ? l0 : l1;
        #pragma unroll
        for (int r = 0; r < 4; ++r) {
            float lq = __shfl(lsrc, quad * 4 + r);
            float inv = 1.f / lq;
            int q = q0 + wq + qg * 16 + quad * 4 + r;
            size_t rowbase = ((size_t)(b * Nseq + q)) * Cdim + h * Dd;
            #pragma unroll
            for (int nt = 0; nt < 4; ++nt)
                ao[rowbase + nt * 16 + ml] = f2bf(o[qg][nt][r] * inv);
        }
    }
}

extern "C" void kernel_launch(void* const* d_in, const int* in_sizes, int n_in,
                              void* d_out, int out_size, void* d_ws, size_t ws_size,
                              hipStream_t stream) {
    const float* x      = (const float*)d_in[0];
    const float* w_qkv  = (const float*)d_in[1];
    const float* w_proj = (const float*)d_in[2];
    const float* b_proj = (const float*)d_in[3];
    float* out = (float*)d_out;

    const size_t M8 = (size_t)8 * 1024 * 1024;
    unsigned short* qb     = (unsigned short*)d_ws;
    unsigned short* kb     = qb + M8;
    unsigned short* vt     = kb + M8;                  // (B,H,D,N)
    unsigned short* xb     = vt + M8;                  // reused as aob
    unsigned short* wqkvt  = xb + M8;                  // 3072 x 1024
    unsigned short* wprojt = wqkvt + 3 * 1024 * 1024;  // 1024 x 1024
    float2*         rope   = (float2*)(wprojt + 1024 * 1024);  // 1024 x 32
    unsigned short* aob    = xb;   // alias: xb dead after gemm0

    prep<<<9344, 256, 0, stream>>>(x, w_qkv, w_proj, xb, wqkvt, wprojt, rope);

    gemm_bf16<0><<<dim3(24, 64), 256, 0, stream>>>(xb, wqkvt, nullptr, rope,
                                                   qb, kb, vt, nullptr);

    attn_flash_mfma<<<dim3(128, 8), 256, 0, stream>>>(qb, kb, vt, aob);

    gemm_bf16<1><<<dim3(8, 64), 256, 0, stream>>>(aob, wprojt, b_proj, nullptr,
                                                  nullptr, nullptr, nullptr, out);
}

// Round 8
// 228.404 us; speedup vs baseline: 1.2596x; 1.0652x over previous
//
#include <hip/hip_runtime.h>
#include <hip/hip_bf16.h>
#include <math.h>

#define Bsz  8
#define Nseq 1024
#define Cdim 1024
#define Hh   16
#define Dd   64

typedef short short8 __attribute__((ext_vector_type(8)));
typedef float floatx4 __attribute__((ext_vector_type(4)));

__device__ __forceinline__ unsigned short f2bf(float f) {
    __hip_bfloat16 h = __float2bfloat16(f);
    return __builtin_bit_cast(unsigned short, h);
}

// async 16B global -> LDS. LDS dest is wave-uniform base + lane*16 (HW rule).
__device__ __forceinline__ void async16(const void* g, void* l) {
    __builtin_amdgcn_global_load_lds(
        (const __attribute__((address_space(1))) unsigned int*)g,
        (__attribute__((address_space(3))) unsigned int*)l, 16, 0, 0);
}

// pack two fp32 -> two bf16 (round-half-up) in one dword
__device__ __forceinline__ unsigned pack_bf16(float lo, float hi) {
    unsigned ulo = __float_as_uint(lo) + 0x8000u;
    unsigned uhi = __float_as_uint(hi) + 0x8000u;
    return __builtin_amdgcn_perm(uhi, ulo, 0x07060302);  // [ulo>>16, uhi>>16]
}

// one-instruction packed fp32x2 -> bf16x2 (RNE); replaces 3-instr pack_bf16
__device__ __forceinline__ unsigned cvt_pk_bf16(float lo, float hi) {
    unsigned r;
    asm("v_cvt_pk_bf16_f32 %0, %1, %2" : "=v"(r) : "v"(lo), "v"(hi));
    return r;
}

// one-instruction 2^x (log2(e) is pre-folded into the Q scale)
__device__ __forceinline__ float exp2_raw(float x) {
    float r;
    asm("v_exp_f32 %0, %1" : "=v"(r) : "v"(x));
    return r;
}

// ---------------------------------------------------------------------------
// PREP (fused): [0,8192) convert X fp32->bf16; [8192,8960) transpose w_qkv;
// [8960,9216) transpose w_proj; [9216,9344) RoPE table.
// ---------------------------------------------------------------------------
__global__ __launch_bounds__(256) void prep(
    const float* __restrict__ x, const float* __restrict__ w_qkv,
    const float* __restrict__ w_proj,
    unsigned short* __restrict__ xb, unsigned short* __restrict__ wqkvt,
    unsigned short* __restrict__ wprojt, float2* __restrict__ rope)
{
    __shared__ float T[64][65];
    const int blk = blockIdx.x;
    const int tid = threadIdx.x;

    if (blk < 8192) {
        int i = blk * 256 + tid;
        float4 v = ((const float4*)x)[i];
        ushort4 u;
        u.x = f2bf(v.x); u.y = f2bf(v.y); u.z = f2bf(v.z); u.w = f2bf(v.w);
        ((ushort4*)xb)[i] = u;
        return;
    }
    if (blk < 9216) {
        const float* in;
        unsigned short* out;
        int R = 1024, Ccols, c0, r0;
        if (blk < 8960) {
            int b2 = blk - 8192;
            in = w_qkv; out = wqkvt; Ccols = 3072;
            c0 = (b2 % 48) * 64; r0 = (b2 / 48) * 64;
        } else {
            int b2 = blk - 8960;
            in = w_proj; out = wprojt; Ccols = 1024;
            c0 = (b2 % 16) * 64; r0 = (b2 / 16) * 64;
        }
        for (int i = tid; i < 4096; i += 256) {
            int r = i >> 6, c = i & 63;
            T[r][c] = in[(size_t)(r0 + r) * Ccols + c0 + c];
        }
        __syncthreads();
        for (int i = tid; i < 4096; i += 256) {
            int rr = i >> 6, cc = i & 63;
            out[(size_t)(c0 + rr) * R + r0 + cc] = f2bf(T[cc][rr]);
        }
        return;
    }
    {
        int i = (blk - 9216) * 256 + tid;     // 0..32767
        int n = i >> 5, p = i & 31;
        float omega = __expf(-(float)p * 0.2878231366242557f);
        float sv, cv;
        sincosf((float)n * omega, &sv, &cv);
        rope[i] = make_float2(cv, sv);
    }
}

// ---------------------------------------------------------------------------
// bf16 MFMA GEMM, BK=64 (16 K-iters, 32 KB LDS, XOR swizzle, XCD-aware
// block remap). Proven round-2 version (~80 us for MODE 0).
// MODE 0: N=3072; epilogue RoPE-scatters q,k -> (B,H,N,D); v -> vt (B,H,D,N).
//         q is pre-scaled by 0.125*log2(e) so attention uses raw v_exp_f32.
// MODE 1: N=1024, +bias -> fp32 out.
// ---------------------------------------------------------------------------
template <int MODE>
__global__ __launch_bounds__(256) void gemm_bf16(
    const unsigned short* __restrict__ A, const unsigned short* __restrict__ Bt,
    const float* __restrict__ bias, const float2* __restrict__ rope,
    unsigned short* __restrict__ qb, unsigned short* __restrict__ kb,
    unsigned short* __restrict__ vtb, float* __restrict__ out)
{
    const int K = 1024;
    __shared__ short SM[2][128][64];   // [0]=As, [1]=Bs; reused by epilogue
    const int tid  = threadIdx.x;
    const int wave = tid >> 6, lane = tid & 63;
    const int ml = lane & 15, quad = lane >> 4;
    const int wm = wave >> 1, wn = wave & 1;

    // XCD-aware bijective remap (nwg % 8 == 0 for both modes)
    int lin = blockIdx.y * gridDim.x + blockIdx.x;
    const int nwg = gridDim.x * gridDim.y;
    lin = (lin & 7) * (nwg >> 3) + (lin >> 3);
    const int bx = lin % gridDim.x, by = lin / gridDim.x;
    const int bm = by * 128, bn = bx * 128;

    const int lr     = lane >> 3;                 // row within 8-row group
    const int lchunk = ((lane & 7) ^ lr) * 8;     // swizzled source chunk (shorts)

    floatx4 acc[4][4] = {};

    for (int k0 = 0; k0 < K; k0 += 64) {
        #pragma unroll
        for (int t = 0; t < 4; ++t) {
            int r8  = (wave * 4 + t) * 8;
            int row = r8 + lr;
            async16(A  + (size_t)(bm + row) * K + k0 + lchunk, &SM[0][r8][0]);
            async16(Bt + (size_t)(bn + row) * K + k0 + lchunk, &SM[1][r8][0]);
        }
        __syncthreads();

        #pragma unroll
        for (int ks = 0; ks < 2; ++ks) {
            const int sl = ((ks * 4 + quad) ^ (ml & 7)) * 8;
            short8 araw[4], braw[4];
            #pragma unroll
            for (int mi = 0; mi < 4; ++mi)
                araw[mi] = *(const short8*)&SM[0][wm * 64 + mi * 16 + ml][sl];
            #pragma unroll
            for (int ni = 0; ni < 4; ++ni)
                braw[ni] = *(const short8*)&SM[1][wn * 64 + ni * 16 + ml][sl];
            #pragma unroll
            for (int mi = 0; mi < 4; ++mi)
                #pragma unroll
                for (int ni = 0; ni < 4; ++ni)
                    acc[mi][ni] = __builtin_amdgcn_mfma_f32_16x16x32_bf16(
                        araw[mi], braw[ni], acc[mi][ni], 0, 0, 0);
        }
        __syncthreads();   // frag reads done before next stage / epilogue reuse
    }

    if (MODE == 0) {
        const int region = bn >> 10;              // 0=q, 1=k, 2=v (block-uniform)
        const int b = bm >> 10;
        if (region < 2) {
            // stage rope slice for rows bm..bm+127: Rs[rl][p], 4096 float2 = 32 KB
            float2* Rs = (float2*)&SM[0][0][0];
            #pragma unroll
            for (int t = 0; t < 16; ++t) {
                int idx = t * 256 + tid;
                Rs[idx] = rope[(size_t)((bm + (idx >> 5)) & 1023) * 32 + (idx & 31)];
            }
            __syncthreads();
            unsigned short* dst = (region == 0) ? qb : kb;
            const float scale = (region == 0) ? 0.1803368801111602f : 1.f;
            const float sgn = (ml & 1) ? 1.f : -1.f;
            #pragma unroll
            for (int ni = 0; ni < 4; ++ni) {
                int col = bn + wn * 64 + ni * 16 + ml;
                int jj = col & 1023;
                int h = jj >> 6, d = jj & 63;
                int p = d >> 1;
                #pragma unroll
                for (int mi = 0; mi < 4; ++mi)
                    #pragma unroll
                    for (int r = 0; r < 4; ++r) {
                        int rl = wm * 64 + mi * 16 + quad * 4 + r;
                        int n  = (bm + rl) & 1023;
                        float val = acc[mi][ni][r];
                        float partner = __shfl_xor(val, 1);
                        float2 cs = Rs[rl * 32 + p];
                        dst[(((size_t)(b * Hh + h)) * Nseq + n) * Dd + d] =
                            f2bf((val * cs.x + sgn * partner * cs.y) * scale);
                    }
            }
        } else {
            // V: transpose via LDS (two 64-col halves), store (B,H,D,N) coalesced
            short* T = &SM[0][0][0];              // [64][132] = 16.9 KB
            const int n0 = bm & 1023;
            #pragma unroll
            for (int hw = 0; hw < 2; ++hw) {
                if (hw) __syncthreads();          // prior half's reads done
                if (wn == hw) {
                    #pragma unroll
                    for (int ni = 0; ni < 4; ++ni) {
                        int dcol = ni * 16 + ml;
                        #pragma unroll
                        for (int mi = 0; mi < 4; ++mi)
                            #pragma unroll
                            for (int r = 0; r < 4; ++r) {
                                int rl = wm * 64 + mi * 16 + quad * 4 + r;
                                T[dcol * 132 + rl] = (short)f2bf(acc[mi][ni][r]);
                            }
                    }
                }
                __syncthreads();
                int h = ((bn & 1023) >> 6) + hw;
                #pragma unroll
                for (int t = 0; t < 8; ++t) {
                    int idx4 = t * 256 + tid;     // 0..2047 ushort4 units
                    int d = idx4 >> 5, seg = idx4 & 31;
                    ushort4 v4 = *(const ushort4*)&T[d * 132 + seg * 4];
                    *(ushort4*)(vtb + (((size_t)(b * Hh + h)) * Dd + d) * Nseq
                                + n0 + seg * 4) = v4;
                }
            }
        }
    } else {
        #pragma unroll
        for (int ni = 0; ni < 4; ++ni) {
            int col = bn + wn * 64 + ni * 16 + ml;
            float bv = bias[col];
            #pragma unroll
            for (int mi = 0; mi < 4; ++mi)
                #pragma unroll
                for (int r = 0; r < 4; ++r) {
                    int row = bm + wm * 64 + mi * 16 + quad * 4 + r;
                    out[(size_t)row * 1024 + col] = acc[mi][ni][r] + bv;
                }
        }
    }
}

// ---------------------------------------------------------------------------
// MFMA flash attention (round-2 proven structure): no-max softmax, 128 q-rows
// per block, software-pipelined V(kt)/K(kt+1) staging, Q fragments hoisted,
// LDS union (34 KB -> 4 blocks/CU), setprio around MFMA clusters.
// exp path: Q pre-scaled by 0.125*log2(e) upstream -> bare v_exp_f32 here.
// P packing: one v_cvt_pk_bf16_f32 per pair (was 3-instr pack_bf16).
// ---------------------------------------------------------------------------
__global__ __launch_bounds__(256, 4) void attn_flash_mfma(
    const unsigned short* __restrict__ qb, const unsigned short* __restrict__ kb,
    const unsigned short* __restrict__ vt, unsigned short* __restrict__ ao)
{
    const int bh  = blockIdx.x;   // 0..127
    const int qt  = blockIdx.y;   // 0..7
    const int tid = threadIdx.x;
    const int wave = tid >> 6, lane = tid & 63;
    const int ml = lane & 15, quad = lane >> 4;
    const int lr = lane >> 3;
    const int lc = ((lane & 7) ^ lr) * 8;

    // 34 KB total: Ks[64][64] | U = union{ Qs[128][64] (prologue only),
    //                                      Vs[64][64] + Ps[4][32][72] }
    __shared__ __attribute__((aligned(16))) short SMEM[17408];
    short (*Ks)[64] = (short(*)[64])SMEM;                 // 4096 shorts
    short* U = SMEM + 4096;
    short (*Qs)[64] = (short(*)[64])U;                    // prologue only
    short (*Vs)[64] = (short(*)[64])U;                    // 4096 shorts
    short (*Ps)[32][72] = (short(*)[32][72])(U + 4096);   // 9216 shorts

    const size_t hbase = (size_t)bh * (Nseq * Dd);
    const size_t vbase = (size_t)bh * 64;
    const int q0 = qt * 128;
    const int wq = wave * 32;
    const int wk = wave * 16;

    #pragma unroll
    for (int t = 0; t < 4; ++t)
        async16(qb + hbase + (size_t)(q0 + wq + t * 8 + lr) * 64 + lc, &Qs[wq + t * 8][0]);
    async16(kb + hbase + (size_t)(wk + lr) * 64 + lc,     &Ks[wk][0]);
    async16(kb + hbase + (size_t)(wk + 8 + lr) * 64 + lc, &Ks[wk + 8][0]);
    __syncthreads();

    short8 qfr[2][2];
    #pragma unroll
    for (int ks = 0; ks < 2; ++ks) {
        const int sl = ((ks * 4 + quad) ^ (ml & 7)) * 8;
        qfr[ks][0] = *(const short8*)&Qs[wq + ml][sl];
        qfr[ks][1] = *(const short8*)&Qs[wq + 16 + ml][sl];
    }
    __syncthreads();   // qfr reads complete in all waves: U reusable (Vs/Ps)

    float l0 = 0.f, l1 = 0.f;
    floatx4 o[2][4] = {};

    for (int kt = 0; kt < 16; ++kt) {
        const int k0r = kt * 64;
        async16(vt + (vbase + wk + lr) * Nseq + k0r + lc,     &Vs[wk][0]);
        async16(vt + (vbase + wk + 8 + lr) * Nseq + k0r + lc, &Vs[wk + 8][0]);

        floatx4 st[2][4] = {};
        __builtin_amdgcn_s_setprio(1);
        #pragma unroll
        for (int ks = 0; ks < 2; ++ks) {
            const int sl = ((ks * 4 + quad) ^ (ml & 7)) * 8;
            #pragma unroll
            for (int kbk = 0; kbk < 4; ++kbk) {
                short8 kf = *(const short8*)&Ks[kbk * 16 + ml][sl];
                st[0][kbk] = __builtin_amdgcn_mfma_f32_16x16x32_bf16(kf, qfr[ks][0], st[0][kbk], 0, 0, 0);
                st[1][kbk] = __builtin_amdgcn_mfma_f32_16x16x32_bf16(kf, qfr[ks][1], st[1][kbk], 0, 0, 0);
            }
        }
        __builtin_amdgcn_s_setprio(0);

        #pragma unroll
        for (int qg = 0; qg < 2; ++qg) {
            float lacc = 0.f;
            #pragma unroll
            for (int kbk = 0; kbk < 4; ++kbk) {
                float e0 = exp2_raw(st[qg][kbk][0]);
                float e1 = exp2_raw(st[qg][kbk][1]);
                float e2 = exp2_raw(st[qg][kbk][2]);
                float e3 = exp2_raw(st[qg][kbk][3]);
                lacc += (e0 + e1) + (e2 + e3);
                uint2 pk;
                pk.x = cvt_pk_bf16(e0, e1);
                pk.y = cvt_pk_bf16(e2, e3);
                *(uint2*)&Ps[wave][qg * 16 + ml][kbk * 16 + quad * 4] = pk;
            }
            if (qg == 0) l0 += lacc; else l1 += lacc;
        }
        __syncthreads();   // V(kt) visible; all waves done with Ks(kt)

        if (kt < 15) {
            const int k1r = k0r + 64;
            async16(kb + hbase + (size_t)(k1r + wk + lr) * 64 + lc,     &Ks[wk][0]);
            async16(kb + hbase + (size_t)(k1r + wk + 8 + lr) * 64 + lc, &Ks[wk + 8][0]);
        }

        __builtin_amdgcn_s_setprio(1);
        #pragma unroll
        for (int ks = 0; ks < 2; ++ks) {
            const int sl = ((ks * 4 + quad) ^ (ml & 7)) * 8;
            short8 pf0 = *(const short8*)&Ps[wave][ml][ks * 32 + quad * 8];
            short8 pf1 = *(const short8*)&Ps[wave][16 + ml][ks * 32 + quad * 8];
            #pragma unroll
            for (int nt = 0; nt < 4; ++nt) {
                short8 vf = *(const short8*)&Vs[nt * 16 + ml][sl];
                o[0][nt] = __builtin_amdgcn_mfma_f32_16x16x32_bf16(pf0, vf, o[0][nt], 0, 0, 0);
                o[1][nt] = __builtin_amdgcn_mfma_f32_16x16x32_bf16(pf1, vf, o[1][nt], 0, 0, 0);
            }
        }
        __builtin_amdgcn_s_setprio(0);
        if (kt < 15)
            __syncthreads();
    }

    l0 += __shfl_xor(l0, 16);
    l0 += __shfl_xor(l0, 32);
    l1 += __shfl_xor(l1, 16);
    l1 += __shfl_xor(l1, 32);

    const int b = bh >> 4, h = bh & 15;
    #pragma unroll
    for (int qg = 0; qg < 2; ++qg) {
        float lsrc = (qg == 0) ? l0 : l1;
        #pragma unroll
        for (int r = 0; r < 4; ++r) {
            float lq = __shfl(lsrc, quad * 4 + r);
            float inv = 1.f / lq;
            int q = q0 + wq + qg * 16 + quad * 4 + r;
            size_t rowbase = ((size_t)(b * Nseq + q)) * Cdim + h * Dd;
            #pragma unroll
            for (int nt = 0; nt < 4; ++nt)
                ao[rowbase + nt * 16 + ml] = f2bf(o[qg][nt][r] * inv);
        }
    }
}

extern "C" void kernel_launch(void* const* d_in, const int* in_sizes, int n_in,
                              void* d_out, int out_size, void* d_ws, size_t ws_size,
                              hipStream_t stream) {
    const float* x      = (const float*)d_in[0];
    const float* w_qkv  = (const float*)d_in[1];
    const float* w_proj = (const float*)d_in[2];
    const float* b_proj = (const float*)d_in[3];
    float* out = (float*)d_out;

    const size_t M8 = (size_t)8 * 1024 * 1024;
    unsigned short* qb     = (unsigned short*)d_ws;
    unsigned short* kb     = qb + M8;
    unsigned short* vt     = kb + M8;                  // (B,H,D,N)
    unsigned short* xb     = vt + M8;                  // reused as aob
    unsigned short* wqkvt  = xb + M8;                  // 3072 x 1024
    unsigned short* wprojt = wqkvt + 3 * 1024 * 1024;  // 1024 x 1024
    float2*         rope   = (float2*)(wprojt + 1024 * 1024);  // 1024 x 32
    unsigned short* aob    = xb;   // alias: xb dead after gemm0

    prep<<<9344, 256, 0, stream>>>(x, w_qkv, w_proj, xb, wqkvt, wprojt, rope);

    gemm_bf16<0><<<dim3(24, 64), 256, 0, stream>>>(xb, wqkvt, nullptr, rope,
                                                   qb, kb, vt, nullptr);

    attn_flash_mfma<<<dim3(128, 8), 256, 0, stream>>>(qb, kb, vt, aob);

    gemm_bf16<1><<<dim3(8, 64), 256, 0, stream>>>(aob, wprojt, b_proj, nullptr,
                                                  nullptr, nullptr, nullptr, out);
}